// Round 13
// baseline (110.596 us; speedup 1.0000x reference)
//
#include <hip/hip_runtime.h>
#include <cstdint>

#define IN_DIM   128
#define OUT_DIM  256
#define NROWS    32768
#define NSTEPS_L 16            // per-wave K-tiles: K_half = 2048 = 16 * 128

typedef unsigned short u16;
typedef __attribute__((ext_vector_type(8)))  __bf16 bf16x8;
typedef __attribute__((ext_vector_type(16))) float  f32x16;
typedef __attribute__((ext_vector_type(4)))  float  f32x4v;

// ---------------------------------------------------------------------------
// Prep: repack fouriercoeffs (2,256,128,16) f32 -> Bpack bf16 [K/8][256][8]
// with k = i*32 + t*16 + g  (t: 0=cos, 1=sin; slot g holds harmonic g+1).
// ---------------------------------------------------------------------------
__global__ __launch_bounds__(256) void kan_prep(const float* __restrict__ C,
                                                u16* __restrict__ Bpack) {
    const int o = threadIdx.x;   // 0..255 output channel
    const int i = blockIdx.x;    // 0..127 input dim
    const int t = blockIdx.y;    // 0=cos, 1=sin
    const float* src = C + (((size_t)(t * OUT_DIM + o) * IN_DIM + i) * 16);
    bf16x8 lo = {}, hi = {};
#pragma unroll
    for (int g = 0; g < 8; ++g) {
        lo[g] = (__bf16)src[g];
        hi[g] = (__bf16)src[8 + g];
    }
    const int ko = i * 4 + t * 2;       // k>>3
    bf16x8* dst = (bf16x8*)Bpack;
    dst[(size_t)ko * OUT_DIM + o]       = lo;   // g = 0..7
    dst[(size_t)(ko + 1) * OUT_DIM + o] = hi;   // g = 8..15
}

// ---------------------------------------------------------------------------
// Fused trig + bf16 MFMA GEMM, v13 = v12 + in-block K-split (ONE change).
//  - v12 validated: in-register A-gen, zero LDS/barriers in main loop,
//    conflicts=0, correct numerics. Its wall was 1 wave/SIMD serial issue
//    (VALU-issue 23.6us + MFMA-pipe 27.3us + exposed latency = 97us).
//  - v13: 128 threads = 2 waves per 64x128 tile; wave kh owns K-half
//    i in [64*kh, 64*kh+64). Both waves run v12's IDENTICAL no-barrier
//    loop; partials merged once at the end via LDS (v8's proven-correct
//    merge). 2048 waves = 2/SIMD: one wave's VALU issue interleaves with
//    the other's MFMA pipe (m114), B latency hidden by the partner wave.
//  - Ledger unchanged: B/FLOP 1/64, A-traffic 0, trig R=4 (23.6us < MFMA
//    27.3us pipe). LDS 32KB/block only for the merge epilogue.
// ---------------------------------------------------------------------------
__global__ __launch_bounds__(128, 2) void kan_gemm(const float* __restrict__ x,
                                                   const u16* __restrict__ Bpack,
                                                   const float* __restrict__ bias,
                                                   float* __restrict__ out) {
    __shared__ __align__(16) float red[64 * 128];   // 32 KB merge scratch

    const int tid  = threadIdx.x;
    const int lane = tid & 63;
    const int kh   = tid >> 6;       // 0..1: K-half this wave owns
    const int la31 = lane & 31;
    const int gh   = lane >> 5;      // 0..1: k-half within each K=16 window
    const int bid  = blockIdx.x;
    const int wn   = bid & 1;        // col group: 128 cols
    const int m0   = (bid >> 1) * 64;

    f32x16 vz;
#pragma unroll
    for (int r = 0; r < 16; ++r) vz[r] = 0.f;
    f32x16 acc[2][4] = {{vz, vz, vz, vz}, {vz, vz, vz, vz}};

    const bf16x8* Bv = (const bf16x8*)Bpack;
    const int bcol = wn * 128 + la31;          // + fn*32 per fragment

    // this wave's x base: rows (la31, la31+32), columns kh*64 + ...
    const float* xr0 = x + (size_t)(m0 + la31) * IN_DIM + kh * 64;
    const float* xr1 = xr0 + (size_t)32 * IN_DIM;

    // Chebyshev chain: 16 harmonics of xv; emit this lane's gh-half as the
    // MFMA A-fragments for the cos window (afc) and sin window (afs).
    auto chain = [&](float xv, bf16x8& afc, bf16x8& afs) {
        float s1, c1;
        __sincosf(xv, &s1, &c1);
        const float t2 = 2.f * c1;
        bf16x8 qc0 = {}, qc1 = {}, qs0 = {}, qs1 = {};
        float cp = c1, sp = s1;                    // harmonic 1
        float cc = t2 * c1 - 1.f, sc = t2 * s1;    // harmonic 2
        qc0[0] = (__bf16)cp;  qs0[0] = (__bf16)sp;
        qc0[1] = (__bf16)cc;  qs0[1] = (__bf16)sc;
#pragma unroll
        for (int g = 3; g <= 16; ++g) {            // 2 FMA per harmonic
            const float cn = t2 * cc - cp;
            const float sn = t2 * sc - sp;
            cp = cc; sp = sc; cc = cn; sc = sn;
            const int idx = g - 1;                 // slot = harmonic-1
            if (idx < 8) { qc0[idx] = (__bf16)cc;      qs0[idx] = (__bf16)sc; }
            else         { qc1[idx - 8] = (__bf16)cc;  qs1[idx - 8] = (__bf16)sc; }
        }
        afc = gh ? qc1 : qc0;   // 4 v_cndmask each
        afs = gh ? qs1 : qs0;
    };

    // x double-buffer (4 floats per row per kt, 16B-aligned)
    f32x4v xa = *(const f32x4v*)(xr0);
    f32x4v xb = *(const f32x4v*)(xr1);

    for (int kt = 0; kt < NSTEPS_L; ++kt) {
        const int ktn = (kt + 1) & (NSTEPS_L - 1);
        const f32x4v xa_n = *(const f32x4v*)(xr0 + ktn * 4);
        const f32x4v xb_n = *(const f32x4v*)(xr1 + ktn * 4);

#pragma unroll
        for (int i = 0; i < 4; ++i) {
            // B fragments for this i's cos & sin windows.
            // i_glob = kh*64 + kt*4 + i; ko = i_glob*4 + t*2 + gh
            const size_t koc = (size_t)((kh * 64 + kt * 4 + i) * 4 + gh);
            bf16x8 bgc[4], bgs[4];
#pragma unroll
            for (int fn = 0; fn < 4; ++fn) {
                bgc[fn] = Bv[koc * OUT_DIM + bcol + fn * 32];
                bgs[fn] = Bv[(koc + 2) * OUT_DIM + bcol + fn * 32];
            }

            // A fragments: harmonic chains for this lane's two rows
            bf16x8 afc0, afs0, afc1, afs1;
            chain(xa[i], afc0, afs0);
            chain(xb[i], afc1, afs1);

            // cos window (k = i_glob*32 + 0..15)
#pragma unroll
            for (int fn = 0; fn < 4; ++fn) {
                acc[0][fn] = __builtin_amdgcn_mfma_f32_32x32x16_bf16(afc0, bgc[fn], acc[0][fn], 0, 0, 0);
                acc[1][fn] = __builtin_amdgcn_mfma_f32_32x32x16_bf16(afc1, bgc[fn], acc[1][fn], 0, 0, 0);
            }
            // sin window (k = i_glob*32 + 16..31)
#pragma unroll
            for (int fn = 0; fn < 4; ++fn) {
                acc[0][fn] = __builtin_amdgcn_mfma_f32_32x32x16_bf16(afs0, bgs[fn], acc[0][fn], 0, 0, 0);
                acc[1][fn] = __builtin_amdgcn_mfma_f32_32x32x16_bf16(afs1, bgs[fn], acc[1][fn], 0, 0, 0);
            }
        }
        xa = xa_n;
        xb = xb_n;
    }

    // ---- merge K-half partials via LDS, then store (v8-proven pattern) ----
    // C/D layout (verified): col = lane&31 (+fn*32), row = (r&3)+8*(r>>2)+4*gh
    if (kh == 1) {
#pragma unroll
        for (int fn = 0; fn < 4; ++fn) {
            const int colL = fn * 32 + la31;           // 0..127 block-local
#pragma unroll
            for (int fm = 0; fm < 2; ++fm) {
                const int rbase = fm * 32 + 4 * gh;
#pragma unroll
                for (int r = 0; r < 16; ++r) {
                    const int row = rbase + (r & 3) + 8 * (r >> 2);
                    red[row * 128 + colL] = acc[fm][fn][r];
                }
            }
        }
    }
    __syncthreads();
    if (kh == 0) {
#pragma unroll
        for (int fn = 0; fn < 4; ++fn) {
            const int colL = fn * 32 + la31;
            const int col  = wn * 128 + colL;
            const float bv = bias[col];
#pragma unroll
            for (int fm = 0; fm < 2; ++fm) {
                const int rbase = fm * 32 + 4 * gh;
#pragma unroll
                for (int r = 0; r < 16; ++r) {
                    const int row = rbase + (r & 3) + 8 * (r >> 2);
                    out[(size_t)(m0 + row) * OUT_DIM + col] =
                        acc[fm][fn][r] + red[row * 128 + colL] + bv;
                }
            }
        }
    }
}

extern "C" void kernel_launch(void* const* d_in, const int* in_sizes, int n_in,
                              void* d_out, int out_size, void* d_ws, size_t ws_size,
                              hipStream_t stream) {
    const float* x    = (const float*)d_in[0];   // (32768, 128) f32
    const float* fc   = (const float*)d_in[1];   // (2, 256, 128, 16) f32
    const float* bias = (const float*)d_in[2];   // (1, 256) f32
    float* out        = (float*)d_out;           // (32768, 256) f32
    u16* Bpack        = (u16*)d_ws;              // 4096*256*2 B = 2 MB scratch

    kan_prep<<<dim3(IN_DIM, 2), OUT_DIM, 0, stream>>>(fc, Bpack);
    kan_gemm<<<dim3(NROWS / 64 * 2), 128, 0, stream>>>(x, Bpack, bias, out);
}